// Round 1
// baseline (322.394 us; speedup 1.0000x reference)
//
#include <hip/hip_runtime.h>
#include <hip/hip_bf16.h>

#define BB 16
#define CC 512
#define LL 2048

typedef float f32x4 __attribute__((ext_vector_type(4)));
typedef short s16x8 __attribute__((ext_vector_type(8)));

static __device__ __forceinline__ float bf2f(unsigned short u) {
    union { unsigned int i; float f; } v; v.i = ((unsigned int)u) << 16; return v.f;
}
static __device__ __forceinline__ unsigned short f2bf(float f) {
    union { float fv; unsigned int i; } v; v.fv = f;
    unsigned int x = v.i;
    return (unsigned short)((x + 0x7FFFu + ((x >> 16) & 1u)) >> 16);  // RNE
}

// ---------------- K0: cast gate_w f32 -> bf16 [512][512] ----------------
__global__ void k0_cast(const float* __restrict__ gw, unsigned short* __restrict__ gwb) {
    int i = blockIdx.x * 256 + threadIdx.x;
    if (i < CC * CC) gwb[i] = f2bf(gw[i]);
}

// ------- K1: RMS over C per (b,l); write inv_rms + x_norm^T bf16 [B][L][C] -------
__global__ __launch_bounds__(256) void k1_rms_t(
    const float* __restrict__ x, const float* __restrict__ pre_w,
    unsigned short* __restrict__ xnt, float* __restrict__ invr) {
    __shared__ float tile[CC * 17];      // [c][l] padded stride 17
    __shared__ float sred[256];
    __shared__ float invs[16];
    const int tid = threadIdx.x;
    const int b  = blockIdx.x >> 7;      // 128 l-tiles of 16
    const int lt = blockIdx.x & 127;
    const int l0 = lt * 16;
    const float* xb = x + (size_t)(b * CC) * LL + l0;

    for (int i = tid; i < CC * 16; i += 256) {
        int c = i >> 4, l = i & 15;
        tile[c * 17 + l] = xb[(size_t)c * LL + l];
    }
    __syncthreads();
    {
        int l = tid & 15, g = tid >> 4;  // 16 partials per l
        float ss = 0.f;
        for (int c = g; c < CC; c += 16) { float v = tile[c * 17 + l]; ss += v * v; }
        sred[g * 16 + l] = ss;
    }
    __syncthreads();
    if (tid < 16) {
        float s = 0.f;
        for (int g2 = 0; g2 < 16; ++g2) s += sred[g2 * 16 + tid];
        float iv = rsqrtf(s * (1.0f / CC) + 1e-5f);
        invs[tid] = iv;
        invr[b * LL + l0 + tid] = iv;
    }
    __syncthreads();
    unsigned short* xo = xnt + ((size_t)b * LL + l0) * CC;
    for (int i = tid; i < CC * 16; i += 256) {
        int l = i >> 9, c = i & 511;
        xo[(size_t)l * CC + c] = f2bf(tile[c * 17 + l] * invs[l] * pre_w[c]);
    }
}

// ------- K2: per-batch GEMM gate[d][l] = silu(sum_c gw[d][c]*xnT[l][c] + gb[d]) -------
// 128x128 tile, BK=64, 4 waves (2x2 of 64x64), mfma_f32_16x16x32_bf16.
__global__ __launch_bounds__(256) void k2_gemm(
    const unsigned short* __restrict__ gwb,   // A [512][512] row-major (d,c)
    const unsigned short* __restrict__ xnt,   // B^T [B][2048][512] (l,c)
    const float* __restrict__ gate_b,
    unsigned short* __restrict__ gate) {      // out bf16 [B][512][2048]
    __shared__ unsigned short As[128 * 64];
    __shared__ unsigned short Bs[128 * 64];
    const int tid = threadIdx.x;
    const int w = tid >> 6, l = tid & 63;
    const int nt = blockIdx.x, mt = blockIdx.y, b = blockIdx.z;
    const int m0 = mt * 128, n0 = nt * 128;
    const unsigned short* Ab = gwb;
    const unsigned short* Bb = xnt + (size_t)b * LL * CC;

    f32x4 acc[4][4] = {};
    const int rsub = l >> 3;        // 0..7  (row within 8-row chunk)
    const int cs8  = (l & 7) * 8;   // short offset within 64-short row (16B per lane)
    const int lo = l & 15, hi = l >> 4;
    const int wm = (w >> 1) * 64, wn = (w & 1) * 64;

    for (int k0 = 0; k0 < CC; k0 += 64) {
        __syncthreads();   // previous tile's ds_reads done before overwrite
        #pragma unroll
        for (int j = 0; j < 4; ++j) {
            int row = w * 32 + j * 8 + rsub;
            __builtin_amdgcn_global_load_lds(
                (const __attribute__((address_space(1))) void*)(Ab + (size_t)(m0 + row) * CC + k0 + cs8),
                (__attribute__((address_space(3))) void*)(As + (w * 32 + j * 8) * 64),
                16, 0, 0);
            __builtin_amdgcn_global_load_lds(
                (const __attribute__((address_space(1))) void*)(Bb + (size_t)(n0 + row) * CC + k0 + cs8),
                (__attribute__((address_space(3))) void*)(Bs + (w * 32 + j * 8) * 64),
                16, 0, 0);
        }
        __syncthreads();   // drains vmcnt (compiler emits vmcnt(0) before s_barrier)
        #pragma unroll
        for (int kk = 0; kk < 2; ++kk) {
            s16x8 af[4], bf[4];
            #pragma unroll
            for (int mi = 0; mi < 4; ++mi)
                af[mi] = *(const s16x8*)(As + (wm + mi * 16 + lo) * 64 + kk * 32 + hi * 8);
            #pragma unroll
            for (int ni = 0; ni < 4; ++ni)
                bf[ni] = *(const s16x8*)(Bs + (wn + ni * 16 + lo) * 64 + kk * 32 + hi * 8);
            #pragma unroll
            for (int mi = 0; mi < 4; ++mi)
                #pragma unroll
                for (int ni = 0; ni < 4; ++ni)
                    acc[mi][ni] = __builtin_amdgcn_mfma_f32_16x16x32_bf16(
                        af[mi], bf[ni], acc[mi][ni], 0, 0, 0);
        }
    }
    // epilogue: +bias, SiLU, store bf16.  D mapping: col=lane&15, row=(lane>>4)*4+r
    #pragma unroll
    for (int mi = 0; mi < 4; ++mi) {
        #pragma unroll
        for (int ni = 0; ni < 4; ++ni) {
            int n = n0 + wn + ni * 16 + lo;
            int d0 = m0 + wm + mi * 16 + hi * 4;
            #pragma unroll
            for (int r = 0; r < 4; ++r) {
                int d = d0 + r;
                float z = acc[mi][ni][r] + gate_b[d];
                float s = z / (1.0f + __expf(-z));
                gate[((size_t)(b * CC + d)) * LL + n] = f2bf(s);
            }
        }
    }
}

// ------- K3: fused conv(7 taps) * gate -> post-RMS -> logits dot -------
__global__ __launch_bounds__(256) void k3_final(
    const float* __restrict__ x, const float* __restrict__ invr,
    const unsigned short* __restrict__ gate,
    const float* __restrict__ cw0, const float* __restrict__ cb0,
    const float* __restrict__ cw1, const float* __restrict__ cb1,
    const float* __restrict__ cw2, const float* __restrict__ cb2,
    const float* __restrict__ pre_w, const float* __restrict__ post_w,
    const float* __restrict__ lw, float* __restrict__ out) {
    __shared__ float tap[CC][8];
    __shared__ float biasS[CC], preS[CC], lwS[CC], pwlwS[CC];
    __shared__ float ivs[72];
    __shared__ float red[3 * 256];
    const int tid = threadIdx.x;
    const int lt = blockIdx.x, b = blockIdx.y;
    const int l0 = lt * 64;

    for (int c = tid; c < CC; c += 256) {
        float w10 = cw0[c*3], w11 = cw0[c*3+1], w12 = cw0[c*3+2];
        float w20 = cw1[c*3], w21 = cw1[c*3+1], w22 = cw1[c*3+2];
        float w40 = cw2[c*3], w41 = cw2[c*3+1], w42 = cw2[c*3+2];
        tap[c][0] = w40; tap[c][1] = w20; tap[c][2] = w10;
        tap[c][3] = w11 + w21 + w41;
        tap[c][4] = w12; tap[c][5] = w22; tap[c][6] = w42;
        biasS[c] = cb0[c] + cb1[c] + cb2[c];
        preS[c]  = pre_w[c];
        float lwc = lw[c];
        lwS[c] = lwc;
        pwlwS[c] = post_w[c] * lwc;
    }
    for (int i = tid; i < 72; i += 256) {
        int lg = l0 - 4 + i;
        ivs[i] = (lg >= 0 && lg < LL) ? invr[b * LL + lg] : 0.f;
    }
    __syncthreads();

    const int ci = tid >> 6, li = tid & 63;   // ci uniform per wave
    const int lpos = l0 + li;
    float ass = 0.f, adp = 0.f, adx = 0.f;
    for (int c = ci; c < CC; c += 4) {
        const float* xr = x + ((size_t)(b * CC + c)) * LL;
        float xc = xr[lpos];
        float s = tap[c][3] * (xc * ivs[li + 4]);
        if (lpos >= 4)      s += tap[c][0] * xr[lpos - 4] * ivs[li];
        if (lpos >= 2)      s += tap[c][1] * xr[lpos - 2] * ivs[li + 2];
        if (lpos >= 1)      s += tap[c][2] * xr[lpos - 1] * ivs[li + 3];
        if (lpos + 1 < LL)  s += tap[c][4] * xr[lpos + 1] * ivs[li + 5];
        if (lpos + 2 < LL)  s += tap[c][5] * xr[lpos + 2] * ivs[li + 6];
        if (lpos + 4 < LL)  s += tap[c][6] * xr[lpos + 4] * ivs[li + 8];
        float xd = preS[c] * s + biasS[c];
        float g  = bf2f(gate[((size_t)(b * CC + c)) * LL + lpos]);
        float p  = xd * g;
        ass += p * p;
        adp += p * pwlwS[c];
        adx += xc * lwS[c];
    }
    red[tid] = ass; red[256 + tid] = adp; red[512 + tid] = adx;
    __syncthreads();
    if (tid < 64) {
        float s0 = red[tid]       + red[ 64 + tid] + red[128 + tid] + red[192 + tid];
        float s1 = red[256 + tid] + red[320 + tid] + red[384 + tid] + red[448 + tid];
        float s2 = red[512 + tid] + red[576 + tid] + red[640 + tid] + red[704 + tid];
        float ms = s0 * (1.0f / CC);
        out[(size_t)b * LL + l0 + tid] = s2 + rsqrtf(ms + 1e-5f) * s1;
    }
}

extern "C" void kernel_launch(void* const* d_in, const int* in_sizes, int n_in,
                              void* d_out, int out_size, void* d_ws, size_t ws_size,
                              hipStream_t stream) {
    // input order per setup_inputs(): 0 number_log (unused), 1 x, 2 pre_w,
    // 3 conv_w, 4 conv_b, 5 conv1_w, 6 conv1_b, 7 conv2_w, 8 conv2_b,
    // 9 gate_w, 10 gate_b, 11 post_w, 12 logits_w
    const float* x      = (const float*)d_in[1];
    const float* pre_w  = (const float*)d_in[2];
    const float* cw0    = (const float*)d_in[3];
    const float* cb0    = (const float*)d_in[4];
    const float* cw1    = (const float*)d_in[5];
    const float* cb1    = (const float*)d_in[6];
    const float* cw2    = (const float*)d_in[7];
    const float* cb2    = (const float*)d_in[8];
    const float* gw     = (const float*)d_in[9];
    const float* gb     = (const float*)d_in[10];
    const float* post_w = (const float*)d_in[11];
    const float* lw     = (const float*)d_in[12];
    float* out = (float*)d_out;

    // ws layout (bytes): gw_bf16 0..524288 | x_norm_T 524288..34078720 |
    // inv_rms ..34209792 | gate ..67764224   (needs ~67.8 MB)
    char* ws = (char*)d_ws;
    unsigned short* gwb  = (unsigned short*)(ws);
    unsigned short* xnt  = (unsigned short*)(ws + 524288);
    float*          invr = (float*)(ws + 524288 + 33554432);
    unsigned short* gate = (unsigned short*)(ws + 524288 + 33554432 + 131072);

    hipLaunchKernelGGL(k0_cast,  dim3((CC * CC + 255) / 256), dim3(256), 0, stream, gw, gwb);
    hipLaunchKernelGGL(k1_rms_t, dim3(BB * (LL / 16)),        dim3(256), 0, stream, x, pre_w, xnt, invr);
    hipLaunchKernelGGL(k2_gemm,  dim3(LL / 128, CC / 128, BB), dim3(256), 0, stream, gwb, xnt, gb, gate);
    hipLaunchKernelGGL(k3_final, dim3(LL / 64, BB),           dim3(256), 0, stream,
                       x, invr, gate, cw0, cb0, cw1, cb1, cw2, cb2, pre_w, post_w, lw, out);
}

// Round 2
// 105.346 us; speedup vs baseline: 3.0603x; 3.0603x over previous
//
#include <hip/hip_runtime.h>
#include <hip/hip_bf16.h>

#define BB 16
#define CC 512
#define LL 2048

typedef float f32x4 __attribute__((ext_vector_type(4)));
typedef short s16x8 __attribute__((ext_vector_type(8)));

static __device__ __forceinline__ float bf2f(unsigned short u) {
    union { unsigned int i; float f; } v; v.i = ((unsigned int)u) << 16; return v.f;
}
static __device__ __forceinline__ unsigned short f2bf(float f) {
    union { float fv; unsigned int i; } v; v.fv = f;
    unsigned int x = v.i;
    return (unsigned short)((x + 0x7FFFu + ((x >> 16) & 1u)) >> 16);  // RNE
}

// ---------------- K0: cast gate_w f32 -> bf16 [512][512] ----------------
__global__ void k0_cast(const float* __restrict__ gw, unsigned short* __restrict__ gwb) {
    int i = blockIdx.x * 256 + threadIdx.x;
    if (i < CC * CC) gwb[i] = f2bf(gw[i]);
}

// ------- K1: RMS over C per (b,l); write inv_rms + x_norm^T bf16 [B][L][C] -------
__global__ __launch_bounds__(256) void k1_rms_t(
    const float* __restrict__ x, const float* __restrict__ pre_w,
    unsigned short* __restrict__ xnt, float* __restrict__ invr) {
    __shared__ float tile[CC * 17];      // [c][l] padded stride 17
    __shared__ float sred[256];
    __shared__ float invs[16];
    const int tid = threadIdx.x;
    const int b  = blockIdx.x >> 7;      // 128 l-tiles of 16
    const int lt = blockIdx.x & 127;
    const int l0 = lt * 16;
    const float* xb = x + (size_t)(b * CC) * LL + l0;

    for (int i = tid; i < CC * 16; i += 256) {
        int c = i >> 4, l = i & 15;
        tile[c * 17 + l] = xb[(size_t)c * LL + l];
    }
    __syncthreads();
    {
        int l = tid & 15, g = tid >> 4;  // 16 partials per l
        float ss = 0.f;
        for (int c = g; c < CC; c += 16) { float v = tile[c * 17 + l]; ss += v * v; }
        sred[g * 16 + l] = ss;
    }
    __syncthreads();
    if (tid < 16) {
        float s = 0.f;
        for (int g2 = 0; g2 < 16; ++g2) s += sred[g2 * 16 + tid];
        float iv = rsqrtf(s * (1.0f / CC) + 1e-5f);
        invs[tid] = iv;
        invr[b * LL + l0 + tid] = iv;
    }
    __syncthreads();
    unsigned short* xo = xnt + ((size_t)b * LL + l0) * CC;
    for (int i = tid; i < CC * 16; i += 256) {
        int l = i >> 9, c = i & 511;
        xo[(size_t)l * CC + c] = f2bf(tile[c * 17 + l] * invs[l] * pre_w[c]);
    }
}

// ------- K2: per-batch GEMM gate[d][l] = silu(sum_c gw[d][c]*xnT[l][c] + gb[d]) -------
__global__ __launch_bounds__(256) void k2_gemm(
    const unsigned short* __restrict__ gwb,   // A [512][512] row-major (d,c)
    const unsigned short* __restrict__ xnt,   // B^T [B][2048][512] (l,c)
    const float* __restrict__ gate_b,
    unsigned short* __restrict__ gate) {      // out bf16 [B][512][2048]
    __shared__ unsigned short As[128 * 64];
    __shared__ unsigned short Bs[128 * 64];
    const int tid = threadIdx.x;
    const int w = tid >> 6, l = tid & 63;
    const int nt = blockIdx.x, mt = blockIdx.y, b = blockIdx.z;
    const int m0 = mt * 128, n0 = nt * 128;
    const unsigned short* Ab = gwb;
    const unsigned short* Bb = xnt + (size_t)b * LL * CC;

    f32x4 acc[4][4] = {};
    const int rsub = l >> 3;
    const int cs8  = (l & 7) * 8;
    const int lo = l & 15, hi = l >> 4;
    const int wm = (w >> 1) * 64, wn = (w & 1) * 64;

    for (int k0 = 0; k0 < CC; k0 += 64) {
        __syncthreads();
        #pragma unroll
        for (int j = 0; j < 4; ++j) {
            int row = w * 32 + j * 8 + rsub;
            __builtin_amdgcn_global_load_lds(
                (const __attribute__((address_space(1))) void*)(Ab + (size_t)(m0 + row) * CC + k0 + cs8),
                (__attribute__((address_space(3))) void*)(As + (w * 32 + j * 8) * 64),
                16, 0, 0);
            __builtin_amdgcn_global_load_lds(
                (const __attribute__((address_space(1))) void*)(Bb + (size_t)(n0 + row) * CC + k0 + cs8),
                (__attribute__((address_space(3))) void*)(Bs + (w * 32 + j * 8) * 64),
                16, 0, 0);
        }
        __syncthreads();
        #pragma unroll
        for (int kk = 0; kk < 2; ++kk) {
            s16x8 af[4], bf[4];
            #pragma unroll
            for (int mi = 0; mi < 4; ++mi)
                af[mi] = *(const s16x8*)(As + (wm + mi * 16 + lo) * 64 + kk * 32 + hi * 8);
            #pragma unroll
            for (int ni = 0; ni < 4; ++ni)
                bf[ni] = *(const s16x8*)(Bs + (wn + ni * 16 + lo) * 64 + kk * 32 + hi * 8);
            #pragma unroll
            for (int mi = 0; mi < 4; ++mi)
                #pragma unroll
                for (int ni = 0; ni < 4; ++ni)
                    acc[mi][ni] = __builtin_amdgcn_mfma_f32_16x16x32_bf16(
                        af[mi], bf[ni], acc[mi][ni], 0, 0, 0);
        }
    }
    #pragma unroll
    for (int mi = 0; mi < 4; ++mi) {
        #pragma unroll
        for (int ni = 0; ni < 4; ++ni) {
            int n = n0 + wn + ni * 16 + lo;
            int d0 = m0 + wm + mi * 16 + hi * 4;
            #pragma unroll
            for (int r = 0; r < 4; ++r) {
                int d = d0 + r;
                float z = acc[mi][ni][r] + gate_b[d];
                float s = z / (1.0f + __expf(-z));
                gate[((size_t)(b * CC + d)) * LL + n] = f2bf(s);
            }
        }
    }
}

// ------- K3a: fused conv(7 taps)*gate partials over a 64-channel chunk -------
// grid (L/128, C/64, B), 256 thr. Thread: 4 consecutive l (float4), 8 channels.
// part[b][cc][l][3] = {sum p^2, sum p*post_w*lw, sum x*lw} over the chunk.
__global__ __launch_bounds__(256) void k3a(
    const float* __restrict__ x, const float* __restrict__ invr,
    const unsigned short* __restrict__ gate,
    const float* __restrict__ cw0, const float* __restrict__ cb0,
    const float* __restrict__ cw1, const float* __restrict__ cb1,
    const float* __restrict__ cw2, const float* __restrict__ cb2,
    const float* __restrict__ pre_w, const float* __restrict__ post_w,
    const float* __restrict__ lw, float* __restrict__ part) {
    __shared__ float tapS[64][8];
    __shared__ float biasS[64], preS[64], lwS[64], pwlwS[64];
    __shared__ float ivs[136];
    __shared__ float red[8][128][3];
    const int tid = threadIdx.x;
    const int lt = blockIdx.x;     // 0..15
    const int cc = blockIdx.y;     // 0..7
    const int b  = blockIdx.z;
    const int l0 = lt * 128;
    const int c0 = cc * 64;

    if (tid < 64) {
        int c = c0 + tid;
        float w10 = cw0[c*3], w11 = cw0[c*3+1], w12 = cw0[c*3+2];
        float w20 = cw1[c*3], w21 = cw1[c*3+1], w22 = cw1[c*3+2];
        float w40 = cw2[c*3], w41 = cw2[c*3+1], w42 = cw2[c*3+2];
        tapS[tid][0] = w40; tapS[tid][1] = w20; tapS[tid][2] = w10;
        tapS[tid][3] = w11 + w21 + w41;
        tapS[tid][4] = w12; tapS[tid][5] = w22; tapS[tid][6] = w42;
        biasS[tid] = cb0[c] + cb1[c] + cb2[c];
        preS[tid]  = pre_w[c];
        float lwc = lw[c];
        lwS[tid] = lwc;
        pwlwS[tid] = post_w[c] * lwc;
    }
    if (tid < 136) {
        int lg = l0 - 4 + tid;
        ivs[tid] = (lg >= 0 && lg < LL) ? invr[b * LL + lg] : 0.f;
    }
    __syncthreads();

    const int li = tid & 31, ci = tid >> 5;
    const int lq = l0 + li * 4;
    float iv[12];
    #pragma unroll
    for (int j = 0; j < 12; ++j) iv[j] = ivs[li * 4 + j];

    const int ia = (lq - 4 < 0) ? 0 : lq - 4;
    const int ic = (lq + 4 > LL - 4) ? LL - 4 : lq + 4;

    float ass[4] = {}, adp[4] = {}, adx[4] = {};
    const float* xbase = x + ((size_t)(b * CC + c0)) * LL;
    const unsigned short* gbase = gate + ((size_t)(b * CC + c0)) * LL;

    #pragma unroll
    for (int j = 0; j < 8; ++j) {
        const int cl = ci * 8 + j;
        const float* xr = xbase + (size_t)cl * LL;
        f32x4 xa = *(const f32x4*)(xr + ia);
        f32x4 xm = *(const f32x4*)(xr + lq);
        f32x4 xc = *(const f32x4*)(xr + ic);
        uint2 gu = *(const uint2*)(gbase + (size_t)cl * LL + lq);
        float g[4];
        g[0] = bf2f((unsigned short)(gu.x & 0xffff));
        g[1] = bf2f((unsigned short)(gu.x >> 16));
        g[2] = bf2f((unsigned short)(gu.y & 0xffff));
        g[3] = bf2f((unsigned short)(gu.y >> 16));
        float z[12];
        #pragma unroll
        for (int r = 0; r < 4; ++r) {
            z[r]     = xa[r] * iv[r];
            z[r + 4] = xm[r] * iv[r + 4];
            z[r + 8] = xc[r] * iv[r + 8];
        }
        const float t0 = tapS[cl][0], t1 = tapS[cl][1], t2 = tapS[cl][2],
                    t3 = tapS[cl][3], t4 = tapS[cl][4], t5 = tapS[cl][5],
                    t6 = tapS[cl][6];
        const float pre = preS[cl], bias = biasS[cl], pwlw = pwlwS[cl], lwc = lwS[cl];
        #pragma unroll
        for (int k = 0; k < 4; ++k) {
            float s = t0 * z[k] + t1 * z[k + 2] + t2 * z[k + 3] + t3 * z[k + 4]
                    + t4 * z[k + 5] + t5 * z[k + 6] + t6 * z[k + 8];
            float p = (pre * s + bias) * g[k];
            ass[k] += p * p;
            adp[k] += p * pwlw;
            adx[k] += xm[k] * lwc;
        }
    }
    #pragma unroll
    for (int k = 0; k < 4; ++k) {
        red[ci][li * 4 + k][0] = ass[k];
        red[ci][li * 4 + k][1] = adp[k];
        red[ci][li * 4 + k][2] = adx[k];
    }
    __syncthreads();
    if (tid < 128) {
        float s0 = 0.f, s1 = 0.f, s2 = 0.f;
        #pragma unroll
        for (int g2 = 0; g2 < 8; ++g2) {
            s0 += red[g2][tid][0];
            s1 += red[g2][tid][1];
            s2 += red[g2][tid][2];
        }
        float* pp = part + (((size_t)(b * 8 + cc)) * LL + l0 + tid) * 3;
        pp[0] = s0; pp[1] = s1; pp[2] = s2;
    }
}

// ------- K3b: combine 8 chunk-partials -> out -------
__global__ __launch_bounds__(256) void k3b(
    const float* __restrict__ part, float* __restrict__ out) {
    int gl = blockIdx.x * 256 + threadIdx.x;   // B*L = 32768
    int b = gl >> 11, l = gl & 2047;
    float s0 = 0.f, s1 = 0.f, s2 = 0.f;
    #pragma unroll
    for (int cc2 = 0; cc2 < 8; ++cc2) {
        const float* pp = part + (((size_t)(b * 8 + cc2)) * LL + l) * 3;
        s0 += pp[0]; s1 += pp[1]; s2 += pp[2];
    }
    out[gl] = s2 + rsqrtf(s0 * (1.0f / CC) + 1e-5f) * s1;
}

extern "C" void kernel_launch(void* const* d_in, const int* in_sizes, int n_in,
                              void* d_out, int out_size, void* d_ws, size_t ws_size,
                              hipStream_t stream) {
    const float* x      = (const float*)d_in[1];
    const float* pre_w  = (const float*)d_in[2];
    const float* cw0    = (const float*)d_in[3];
    const float* cb0    = (const float*)d_in[4];
    const float* cw1    = (const float*)d_in[5];
    const float* cb1    = (const float*)d_in[6];
    const float* cw2    = (const float*)d_in[7];
    const float* cb2    = (const float*)d_in[8];
    const float* gw     = (const float*)d_in[9];
    const float* gb     = (const float*)d_in[10];
    const float* post_w = (const float*)d_in[11];
    const float* lw     = (const float*)d_in[12];
    float* out = (float*)d_out;

    // ws layout (bytes): gw_bf16 0..524288 | x_norm_T 524288..34078720 |
    // inv_rms ..34209792 | gate ..67764224
    // part (3.1MB) aliases x_norm_T (dead after k2).
    char* ws = (char*)d_ws;
    unsigned short* gwb  = (unsigned short*)(ws);
    unsigned short* xnt  = (unsigned short*)(ws + 524288);
    float*          invr = (float*)(ws + 524288 + 33554432);
    unsigned short* gate = (unsigned short*)(ws + 524288 + 33554432 + 131072);
    float*          part = (float*)(ws + 524288);   // alias, dead xnt

    hipLaunchKernelGGL(k0_cast,  dim3((CC * CC + 255) / 256), dim3(256), 0, stream, gw, gwb);
    hipLaunchKernelGGL(k1_rms_t, dim3(BB * (LL / 16)),        dim3(256), 0, stream, x, pre_w, xnt, invr);
    hipLaunchKernelGGL(k2_gemm,  dim3(LL / 128, CC / 128, BB), dim3(256), 0, stream, gwb, xnt, gb, gate);
    hipLaunchKernelGGL(k3a,      dim3(LL / 128, CC / 64, BB), dim3(256), 0, stream,
                       x, invr, gate, cw0, cb0, cw1, cb1, cw2, cb2, pre_w, post_w, lw, part);
    hipLaunchKernelGGL(k3b,      dim3(BB * LL / 256),         dim3(256), 0, stream, part, out);
}

// Round 3
// 85.228 us; speedup vs baseline: 3.7827x; 1.2361x over previous
//
#include <hip/hip_runtime.h>
#include <hip/hip_bf16.h>

#define BB 16
#define CC 512
#define LL 2048

typedef float f32x4 __attribute__((ext_vector_type(4)));
typedef short s16x8 __attribute__((ext_vector_type(8)));

static __device__ __forceinline__ float bf2f(unsigned short u) {
    union { unsigned int i; float f; } v; v.i = ((unsigned int)u) << 16; return v.f;
}
static __device__ __forceinline__ unsigned short f2bf(float f) {
    union { float fv; unsigned int i; } v; v.fv = f;
    unsigned int x = v.i;
    return (unsigned short)((x + 0x7FFFu + ((x >> 16) & 1u)) >> 16);  // RNE
}

// ---------------- K0: cast gate_w f32 -> bf16 [512][512] ----------------
__global__ void k0_cast(const float* __restrict__ gw, unsigned short* __restrict__ gwb) {
    int i = blockIdx.x * 256 + threadIdx.x;
    if (i < CC * CC) gwb[i] = f2bf(gw[i]);
}

// ------- K1: RMS over C per (b,l); write inv_rms + x_norm^T bf16 [B][L][C] -------
// Block = [512 c][32 l] tile. float4 loads, register ssq, transposed f32 LDS tile.
#define K1_ST 524   // f32 stride of transposed tile row (16B-aligned: 524*4 % 16 == 0)
__global__ __launch_bounds__(256) void k1_rms_t(
    const float* __restrict__ x, const float* __restrict__ pre_w,
    unsigned short* __restrict__ xnt, float* __restrict__ invr) {
    __shared__ float tile[32 * K1_ST];   // [l][c], 67.1 KB
    __shared__ float red[32 * 33];       // [l][cr]
    __shared__ float pwS[CC];
    __shared__ float ivS[32];
    const int tid = threadIdx.x;
    const int b  = blockIdx.x >> 6;      // 64 l-tiles of 32
    const int lt = blockIdx.x & 63;
    const int l0 = lt * 32;
    const float* xb = x + (size_t)(b * CC) * LL + l0;

    for (int i = tid; i < CC; i += 256) pwS[i] = pre_w[i];

    const int lq = tid & 7;      // l-quad: l = lq*4..+4
    const int cr = tid >> 3;     // 0..31
    f32x4 ssq = {0.f, 0.f, 0.f, 0.f};
    #pragma unroll
    for (int p = 0; p < 16; ++p) {
        int c = p * 32 + cr;
        f32x4 v = *(const f32x4*)(xb + (size_t)c * LL + lq * 4);
        #pragma unroll
        for (int r = 0; r < 4; ++r) {
            ssq[r] += v[r] * v[r];
            tile[(lq * 4 + r) * K1_ST + c] = v[r];
        }
    }
    #pragma unroll
    for (int r = 0; r < 4; ++r) red[(lq * 4 + r) * 33 + cr] = ssq[r];
    __syncthreads();
    if (tid < 32) {
        float s = 0.f;
        #pragma unroll
        for (int g = 0; g < 32; ++g) s += red[tid * 33 + g];
        float iv = rsqrtf(s * (1.0f / CC) + 1e-5f);
        ivS[tid] = iv;
        invr[b * LL + l0 + tid] = iv;
    }
    __syncthreads();
    unsigned short* xo = xnt + ((size_t)b * LL + l0) * CC;
    #pragma unroll
    for (int p = 0; p < 16; ++p) {
        int q = p * 256 + tid;
        int l = q >> 7, cq = (q & 127) * 4;
        f32x4 t = *(const f32x4*)&tile[l * K1_ST + cq];
        f32x4 w = *(const f32x4*)&pwS[cq];
        float iv = ivS[l];
        ushort4 o;
        o.x = f2bf(t[0] * iv * w[0]);
        o.y = f2bf(t[1] * iv * w[1]);
        o.z = f2bf(t[2] * iv * w[2]);
        o.w = f2bf(t[3] * iv * w[3]);
        *(ushort4*)(xo + (size_t)l * CC + cq) = o;
    }
}

// ------- K2: per-batch GEMM gate[d][l] = silu(sum_c gw[d][c]*xnT[l][c] + gb[d]) -------
// 256x256 tile, BK=64, 8 waves (2Mx4N, 128x64 each), 2-phase double-buffered:
// STAGE(next) -> ds_read(cur) -> 64 MFMA -> one barrier per K-tile.
__global__ __launch_bounds__(512) void k2_gemm(
    const unsigned short* __restrict__ gwb,   // A [512][512] (d,c) row-major
    const unsigned short* __restrict__ xnt,   // B^T [B][2048][512] (l,c)
    const float* __restrict__ gate_b,
    unsigned short* __restrict__ gate) {      // out bf16 [B][512][2048]
    __shared__ unsigned short As[2][256 * 64];   // 64 KB
    __shared__ unsigned short Bs[2][256 * 64];   // 64 KB
    const int tid = threadIdx.x;
    const int w = tid >> 6, lane = tid & 63;
    const int lo = lane & 15, hi = lane >> 4;
    const int wm = w >> 2, wn = w & 3;           // 2M x 4N waves
    const int nt = blockIdx.x, mt = blockIdx.y, b = blockIdx.z;
    const int m0 = mt * 256, n0 = nt * 256;
    const unsigned short* Ab = gwb;
    const unsigned short* Bb = xnt + (size_t)b * LL * CC;

    // stage granule mapping: g = tid + s*512 (0..2047); row=g>>3, col8=(g&7)*8
    #define K2_STAGE(buf, kt)                                                        \
        {                                                                            \
            int k0_ = (kt) * 64;                                                     \
            _Pragma("unroll")                                                        \
            for (int s = 0; s < 4; ++s) {                                            \
                int g = tid + s * 512;                                               \
                int row = g >> 3, col8 = (g & 7) * 8;                                \
                __builtin_amdgcn_global_load_lds(                                    \
                    (const __attribute__((address_space(1))) void*)(Ab + (size_t)(m0 + row) * CC + k0_ + col8), \
                    (__attribute__((address_space(3))) void*)(&As[buf][g * 8]),      \
                    16, 0, 0);                                                       \
                __builtin_amdgcn_global_load_lds(                                    \
                    (const __attribute__((address_space(1))) void*)(Bb + (size_t)(n0 + row) * CC + k0_ + col8), \
                    (__attribute__((address_space(3))) void*)(&Bs[buf][g * 8]),      \
                    16, 0, 0);                                                       \
            }                                                                        \
        }

    f32x4 acc[8][4] = {};
    K2_STAGE(0, 0);
    __syncthreads();

    for (int kt = 0; kt < 8; ++kt) {
        const int cur = kt & 1;
        if (kt < 7) K2_STAGE(cur ^ 1, kt + 1);
        #pragma unroll
        for (int kk = 0; kk < 2; ++kk) {
            s16x8 af[8], bf[4];
            #pragma unroll
            for (int mi = 0; mi < 8; ++mi)
                af[mi] = *(const s16x8*)(&As[cur][(wm * 128 + mi * 16 + lo) * 64 + kk * 32 + hi * 8]);
            #pragma unroll
            for (int ni = 0; ni < 4; ++ni)
                bf[ni] = *(const s16x8*)(&Bs[cur][(wn * 64 + ni * 16 + lo) * 64 + kk * 32 + hi * 8]);
            #pragma unroll
            for (int mi = 0; mi < 8; ++mi)
                #pragma unroll
                for (int ni = 0; ni < 4; ++ni)
                    acc[mi][ni] = __builtin_amdgcn_mfma_f32_16x16x32_bf16(
                        af[mi], bf[ni], acc[mi][ni], 0, 0, 0);
        }
        __syncthreads();   // drains vmcnt(0): next tile staged; cur safe to overwrite
    }

    // epilogue: +bias, SiLU, store bf16. D map: col=lane&15, row=(lane>>4)*4+r
    #pragma unroll
    for (int mi = 0; mi < 8; ++mi) {
        #pragma unroll
        for (int ni = 0; ni < 4; ++ni) {
            int n = n0 + wn * 64 + ni * 16 + lo;
            int d0 = m0 + wm * 128 + mi * 16 + hi * 4;
            #pragma unroll
            for (int r = 0; r < 4; ++r) {
                int d = d0 + r;
                float z = acc[mi][ni][r] + gate_b[d];
                float s = z / (1.0f + __expf(-z));
                gate[((size_t)(b * CC + d)) * LL + n] = f2bf(s);
            }
        }
    }
}

// ------- K3a: fused conv(7 taps)*gate partials over a 64-channel chunk -------
__global__ __launch_bounds__(256) void k3a(
    const float* __restrict__ x, const float* __restrict__ invr,
    const unsigned short* __restrict__ gate,
    const float* __restrict__ cw0, const float* __restrict__ cb0,
    const float* __restrict__ cw1, const float* __restrict__ cb1,
    const float* __restrict__ cw2, const float* __restrict__ cb2,
    const float* __restrict__ pre_w, const float* __restrict__ post_w,
    const float* __restrict__ lw, float* __restrict__ part) {
    __shared__ float tapS[64][8];
    __shared__ float biasS[64], preS[64], lwS[64], pwlwS[64];
    __shared__ float ivs[136];
    __shared__ float red[8][128][3];
    const int tid = threadIdx.x;
    const int lt = blockIdx.x;
    const int cc = blockIdx.y;
    const int b  = blockIdx.z;
    const int l0 = lt * 128;
    const int c0 = cc * 64;

    if (tid < 64) {
        int c = c0 + tid;
        float w10 = cw0[c*3], w11 = cw0[c*3+1], w12 = cw0[c*3+2];
        float w20 = cw1[c*3], w21 = cw1[c*3+1], w22 = cw1[c*3+2];
        float w40 = cw2[c*3], w41 = cw2[c*3+1], w42 = cw2[c*3+2];
        tapS[tid][0] = w40; tapS[tid][1] = w20; tapS[tid][2] = w10;
        tapS[tid][3] = w11 + w21 + w41;
        tapS[tid][4] = w12; tapS[tid][5] = w22; tapS[tid][6] = w42;
        biasS[tid] = cb0[c] + cb1[c] + cb2[c];
        preS[tid]  = pre_w[c];
        float lwc = lw[c];
        lwS[tid] = lwc;
        pwlwS[tid] = post_w[c] * lwc;
    }
    if (tid < 136) {
        int lg = l0 - 4 + tid;
        ivs[tid] = (lg >= 0 && lg < LL) ? invr[b * LL + lg] : 0.f;
    }
    __syncthreads();

    const int li = tid & 31, ci = tid >> 5;
    const int lq = l0 + li * 4;
    float iv[12];
    #pragma unroll
    for (int j = 0; j < 12; ++j) iv[j] = ivs[li * 4 + j];

    const int ia = (lq - 4 < 0) ? 0 : lq - 4;
    const int ic = (lq + 4 > LL - 4) ? LL - 4 : lq + 4;

    float ass[4] = {}, adp[4] = {}, adx[4] = {};
    const float* xbase = x + ((size_t)(b * CC + c0)) * LL;
    const unsigned short* gbase = gate + ((size_t)(b * CC + c0)) * LL;

    #pragma unroll
    for (int j = 0; j < 8; ++j) {
        const int cl = ci * 8 + j;
        const float* xr = xbase + (size_t)cl * LL;
        f32x4 xa = *(const f32x4*)(xr + ia);
        f32x4 xm = *(const f32x4*)(xr + lq);
        f32x4 xc = *(const f32x4*)(xr + ic);
        uint2 gu = *(const uint2*)(gbase + (size_t)cl * LL + lq);
        float g[4];
        g[0] = bf2f((unsigned short)(gu.x & 0xffff));
        g[1] = bf2f((unsigned short)(gu.x >> 16));
        g[2] = bf2f((unsigned short)(gu.y & 0xffff));
        g[3] = bf2f((unsigned short)(gu.y >> 16));
        float z[12];
        #pragma unroll
        for (int r = 0; r < 4; ++r) {
            z[r]     = xa[r] * iv[r];
            z[r + 4] = xm[r] * iv[r + 4];
            z[r + 8] = xc[r] * iv[r + 8];
        }
        const float t0 = tapS[cl][0], t1 = tapS[cl][1], t2 = tapS[cl][2],
                    t3 = tapS[cl][3], t4 = tapS[cl][4], t5 = tapS[cl][5],
                    t6 = tapS[cl][6];
        const float pre = preS[cl], bias = biasS[cl], pwlw = pwlwS[cl], lwc = lwS[cl];
        #pragma unroll
        for (int k = 0; k < 4; ++k) {
            float s = t0 * z[k] + t1 * z[k + 2] + t2 * z[k + 3] + t3 * z[k + 4]
                    + t4 * z[k + 5] + t5 * z[k + 6] + t6 * z[k + 8];
            float p = (pre * s + bias) * g[k];
            ass[k] += p * p;
            adp[k] += p * pwlw;
            adx[k] += xm[k] * lwc;
        }
    }
    #pragma unroll
    for (int k = 0; k < 4; ++k) {
        red[ci][li * 4 + k][0] = ass[k];
        red[ci][li * 4 + k][1] = adp[k];
        red[ci][li * 4 + k][2] = adx[k];
    }
    __syncthreads();
    if (tid < 128) {
        float s0 = 0.f, s1 = 0.f, s2 = 0.f;
        #pragma unroll
        for (int g2 = 0; g2 < 8; ++g2) {
            s0 += red[g2][tid][0];
            s1 += red[g2][tid][1];
            s2 += red[g2][tid][2];
        }
        float* pp = part + (((size_t)(b * 8 + cc)) * LL + l0 + tid) * 3;
        pp[0] = s0; pp[1] = s1; pp[2] = s2;
    }
}

// ------- K3b: combine 8 chunk-partials -> out -------
__global__ __launch_bounds__(256) void k3b(
    const float* __restrict__ part, float* __restrict__ out) {
    int gl = blockIdx.x * 256 + threadIdx.x;   // B*L = 32768
    int b = gl >> 11, l = gl & 2047;
    float s0 = 0.f, s1 = 0.f, s2 = 0.f;
    #pragma unroll
    for (int cc2 = 0; cc2 < 8; ++cc2) {
        const float* pp = part + (((size_t)(b * 8 + cc2)) * LL + l) * 3;
        s0 += pp[0]; s1 += pp[1]; s2 += pp[2];
    }
    out[gl] = s2 + rsqrtf(s0 * (1.0f / CC) + 1e-5f) * s1;
}

extern "C" void kernel_launch(void* const* d_in, const int* in_sizes, int n_in,
                              void* d_out, int out_size, void* d_ws, size_t ws_size,
                              hipStream_t stream) {
    const float* x      = (const float*)d_in[1];
    const float* pre_w  = (const float*)d_in[2];
    const float* cw0    = (const float*)d_in[3];
    const float* cb0    = (const float*)d_in[4];
    const float* cw1    = (const float*)d_in[5];
    const float* cb1    = (const float*)d_in[6];
    const float* cw2    = (const float*)d_in[7];
    const float* cb2    = (const float*)d_in[8];
    const float* gw     = (const float*)d_in[9];
    const float* gb     = (const float*)d_in[10];
    const float* post_w = (const float*)d_in[11];
    const float* lw     = (const float*)d_in[12];
    float* out = (float*)d_out;

    // ws layout (bytes): gw_bf16 0..524288 | x_norm_T 524288..34078720 |
    // inv_rms ..34209792 | gate ..67764224
    // part (3.1MB) aliases x_norm_T (dead after k2).
    char* ws = (char*)d_ws;
    unsigned short* gwb  = (unsigned short*)(ws);
    unsigned short* xnt  = (unsigned short*)(ws + 524288);
    float*          invr = (float*)(ws + 524288 + 33554432);
    unsigned short* gate = (unsigned short*)(ws + 524288 + 33554432 + 131072);
    float*          part = (float*)(ws + 524288);   // alias, dead xnt

    hipLaunchKernelGGL(k0_cast,  dim3((CC * CC + 255) / 256), dim3(256), 0, stream, gw, gwb);
    hipLaunchKernelGGL(k1_rms_t, dim3(BB * (LL / 32)),        dim3(256), 0, stream, x, pre_w, xnt, invr);
    hipLaunchKernelGGL(k2_gemm,  dim3(LL / 256, CC / 256, BB), dim3(512), 0, stream, gwb, xnt, gb, gate);
    hipLaunchKernelGGL(k3a,      dim3(LL / 128, CC / 64, BB), dim3(256), 0, stream,
                       x, invr, gate, cw0, cb0, cw1, cb1, cw2, cb2, pre_w, post_w, lw, part);
    hipLaunchKernelGGL(k3b,      dim3(BB * LL / 256),         dim3(256), 0, stream, part, out);
}

// Round 4
// 79.162 us; speedup vs baseline: 4.0726x; 1.0766x over previous
//
#include <hip/hip_runtime.h>
#include <hip/hip_bf16.h>

#define BB 16
#define CC 512
#define LL 2048

typedef float f32x4 __attribute__((ext_vector_type(4)));
typedef short s16x8 __attribute__((ext_vector_type(8)));

static __device__ __forceinline__ float bf2f(unsigned short u) {
    union { unsigned int i; float f; } v; v.i = ((unsigned int)u) << 16; return v.f;
}
static __device__ __forceinline__ unsigned short f2bf(float f) {
    union { float fv; unsigned int i; } v; v.fv = f;
    unsigned int x = v.i;
    return (unsigned short)((x + 0x7FFFu + ((x >> 16) & 1u)) >> 16);  // RNE
}

// ---------------- K0: cast gate_w f32 -> bf16 [512][512] ----------------
__global__ void k0_cast(const float* __restrict__ gw, unsigned short* __restrict__ gwb) {
    int i = blockIdx.x * 256 + threadIdx.x;
    if (i < CC * CC) gwb[i] = f2bf(gw[i]);
}

// ------- K1: RMS over C per (b,l); write inv_rms + x_norm^T bf16 [B][L][C] -------
// Block = [512 c][32 l] tile. float4 loads, register ssq, bf16 transposed LDS tile.
#define K1_ST 520   // ushort stride (1040 B, 16B-aligned)
__global__ __launch_bounds__(256) void k1_rms_t(
    const float* __restrict__ x, const float* __restrict__ pre_w,
    unsigned short* __restrict__ xnt, float* __restrict__ invr) {
    __shared__ unsigned short tile[32 * K1_ST];   // [l][c] bf16, 33.3 KB
    __shared__ float red[32 * 33];
    __shared__ float pwS[CC];
    __shared__ float ivS[32];
    const int tid = threadIdx.x;
    const int b  = blockIdx.x >> 6;      // 64 l-tiles of 32
    const int lt = blockIdx.x & 63;
    const int l0 = lt * 32;
    const float* xb = x + (size_t)(b * CC) * LL + l0;

    for (int i = tid; i < CC; i += 256) pwS[i] = pre_w[i];

    const int lq = tid & 7;      // l-quad: l = lq*4..+3
    const int cr = tid >> 3;     // 0..31
    f32x4 ssq = {0.f, 0.f, 0.f, 0.f};
    #pragma unroll
    for (int p = 0; p < 16; ++p) {
        int c = p * 32 + cr;
        f32x4 v = *(const f32x4*)(xb + (size_t)c * LL + lq * 4);
        #pragma unroll
        for (int r = 0; r < 4; ++r) {
            ssq[r] += v[r] * v[r];
            tile[(lq * 4 + r) * K1_ST + c] = f2bf(v[r]);
        }
    }
    #pragma unroll
    for (int r = 0; r < 4; ++r) red[(lq * 4 + r) * 33 + cr] = ssq[r];
    __syncthreads();
    if (tid < 32) {
        float s = 0.f;
        #pragma unroll
        for (int g = 0; g < 32; ++g) s += red[tid * 33 + g];
        float iv = rsqrtf(s * (1.0f / CC) + 1e-5f);
        ivS[tid] = iv;
        invr[b * LL + l0 + tid] = iv;
    }
    __syncthreads();
    unsigned short* xo = xnt + ((size_t)b * LL + l0) * CC;
    #pragma unroll
    for (int p = 0; p < 8; ++p) {
        int g = p * 256 + tid;          // 2048 granules of 8 ushorts
        int l = g >> 6, c8 = (g & 63) * 8;
        s16x8 t = *(const s16x8*)&tile[l * K1_ST + c8];
        f32x4 w0 = *(const f32x4*)&pwS[c8];
        f32x4 w1 = *(const f32x4*)&pwS[c8 + 4];
        float iv = ivS[l];
        s16x8 o;
        #pragma unroll
        for (int r = 0; r < 4; ++r) {
            o[r]     = (short)f2bf(bf2f((unsigned short)t[r])     * iv * w0[r]);
            o[r + 4] = (short)f2bf(bf2f((unsigned short)t[r + 4]) * iv * w1[r]);
        }
        *(s16x8*)(xo + (size_t)l * CC + c8) = o;
    }
}

// ------- K2: per-batch GEMM gate[d][l] = silu(sum_c gw[d][c]*xnT[l][c] + gb[d]) -------
// 256x256 tile, BK=64, 8 waves (2Mx4N, 128x64 each). 8-phase schedule:
// per K-tile 4 phases of {ds_read quadrant | stage next-tile granule | barrier |
// lgkmcnt(0) | setprio(1) 16 MFMA setprio(0) | [vmcnt(0) @p3] | barrier}.
// st_16x32 LDS swizzle: linear dest + pre-swizzled global src + swz on read.
__global__ __launch_bounds__(512, 2) void k2_gemm(
    const unsigned short* __restrict__ gwb,   // A [512][512] (d,c) row-major
    const unsigned short* __restrict__ xnt,   // B^T [B][2048][512] (l,c)
    const float* __restrict__ gate_b,
    unsigned short* __restrict__ gate) {      // out bf16 [B][512][2048]
    __shared__ unsigned short As[2][256 * 64];   // 2 x 32 KB
    __shared__ unsigned short Bs[2][256 * 64];   // 2 x 32 KB
    const int tid = threadIdx.x;
    const int w = tid >> 6, lane = tid & 63;
    const int lo = lane & 15, hi = lane >> 4;
    const int wm = w >> 2, wn = w & 3;           // 2M x 4N waves
    const int nt = blockIdx.x, mt = blockIdx.y, b = blockIdx.z;
    const int m0 = mt * 256, n0 = nt * 256;
    const unsigned short* Ab = gwb;
    const unsigned short* Bb = xnt + (size_t)b * LL * CC;

    // stage granule for phase pp: g = pp*512+tid; row=g>>3, kcol=(g&7)*8,
    // source k pre-swizzled so linear LDS write lands swizzled data.
    #define K2_STG(pp, buf, kt_)                                                     \
        {                                                                            \
            int g = (pp) * 512 + tid;                                                \
            int row = g >> 3;                                                        \
            int ks = ((g & 7) * 8) ^ ((row & 4) ? 16 : 0);                           \
            __builtin_amdgcn_global_load_lds(                                        \
                (const __attribute__((address_space(1))) void*)(Ab + (size_t)(m0 + row) * CC + (kt_) * 64 + ks), \
                (__attribute__((address_space(3))) void*)(&As[buf][g * 8]),          \
                16, 0, 0);                                                           \
            __builtin_amdgcn_global_load_lds(                                        \
                (const __attribute__((address_space(1))) void*)(Bb + (size_t)(n0 + row) * CC + (kt_) * 64 + ks), \
                (__attribute__((address_space(3))) void*)(&Bs[buf][g * 8]),          \
                16, 0, 0);                                                           \
        }

    f32x4 acc[8][4] = {};

    // prologue: stage K-tile 0 into buf 0, drain, barrier
    #pragma unroll
    for (int p = 0; p < 4; ++p) K2_STG(p, 0, 0);
    asm volatile("s_waitcnt vmcnt(0)" ::: "memory");
    __builtin_amdgcn_s_barrier();

    #pragma unroll 2
    for (int kt = 0; kt < 8; ++kt) {
        const int cur = kt & 1;
        s16x8 bf[4][2];
        #pragma unroll
        for (int p = 0; p < 4; ++p) {
            // ds-read this phase's A quadrant (and all B frags in phase 0)
            s16x8 af[2][2];
            #pragma unroll
            for (int j = 0; j < 2; ++j) {
                int row = wm * 128 + (p * 2 + j) * 16 + lo;
                int kb = (row & 4) ? 16 : 0;
                #pragma unroll
                for (int kk = 0; kk < 2; ++kk)
                    af[j][kk] = *(const s16x8*)(&As[cur][row * 64 + ((kk * 32 + hi * 8) ^ kb)]);
            }
            if (p == 0) {
                #pragma unroll
                for (int ni = 0; ni < 4; ++ni) {
                    int row = wn * 64 + ni * 16 + lo;
                    int kb = (row & 4) ? 16 : 0;
                    #pragma unroll
                    for (int kk = 0; kk < 2; ++kk)
                        bf[ni][kk] = *(const s16x8*)(&Bs[cur][row * 64 + ((kk * 32 + hi * 8) ^ kb)]);
                }
            }
            // stage next K-tile's phase-p granules (buffer freed at kt-1 end)
            if (kt < 7) K2_STG(p, cur ^ 1, kt + 1);
            __builtin_amdgcn_s_barrier();
            asm volatile("s_waitcnt lgkmcnt(0)" ::: "memory");
            __builtin_amdgcn_sched_barrier(0);
            __builtin_amdgcn_s_setprio(1);
            #pragma unroll
            for (int j = 0; j < 2; ++j)
                #pragma unroll
                for (int ni = 0; ni < 4; ++ni)
                    #pragma unroll
                    for (int kk = 0; kk < 2; ++kk)
                        acc[p * 2 + j][ni] = __builtin_amdgcn_mfma_f32_16x16x32_bf16(
                            af[j][kk], bf[ni][kk], acc[p * 2 + j][ni], 0, 0, 0);
            __builtin_amdgcn_s_setprio(0);
            if (p == 3) asm volatile("s_waitcnt vmcnt(0)" ::: "memory");
            __builtin_amdgcn_s_barrier();
        }
    }

    // epilogue: +bias, SiLU, store bf16. D map: col=lane&15, row=(lane>>4)*4+r
    #pragma unroll
    for (int mi = 0; mi < 8; ++mi) {
        #pragma unroll
        for (int ni = 0; ni < 4; ++ni) {
            int n = n0 + wn * 64 + ni * 16 + lo;
            int d0 = m0 + wm * 128 + mi * 16 + hi * 4;
            #pragma unroll
            for (int r = 0; r < 4; ++r) {
                int d = d0 + r;
                float z = acc[mi][ni][r] + gate_b[d];
                float s = z / (1.0f + __expf(-z));
                gate[((size_t)(b * CC + d)) * LL + n] = f2bf(s);
            }
        }
    }
}

// ------- K3a: fused conv(7 taps)*gate partials over a 64-channel chunk -------
__global__ __launch_bounds__(256) void k3a(
    const float* __restrict__ x, const float* __restrict__ invr,
    const unsigned short* __restrict__ gate,
    const float* __restrict__ cw0, const float* __restrict__ cb0,
    const float* __restrict__ cw1, const float* __restrict__ cb1,
    const float* __restrict__ cw2, const float* __restrict__ cb2,
    const float* __restrict__ pre_w, const float* __restrict__ post_w,
    const float* __restrict__ lw, float* __restrict__ part) {
    __shared__ float tapS[64][8];
    __shared__ float biasS[64], preS[64], lwS[64], pwlwS[64];
    __shared__ float ivs[136];
    __shared__ float red[8][128][3];
    const int tid = threadIdx.x;
    const int lt = blockIdx.x;
    const int cc = blockIdx.y;
    const int b  = blockIdx.z;
    const int l0 = lt * 128;
    const int c0 = cc * 64;

    if (tid < 64) {
        int c = c0 + tid;
        float w10 = cw0[c*3], w11 = cw0[c*3+1], w12 = cw0[c*3+2];
        float w20 = cw1[c*3], w21 = cw1[c*3+1], w22 = cw1[c*3+2];
        float w40 = cw2[c*3], w41 = cw2[c*3+1], w42 = cw2[c*3+2];
        tapS[tid][0] = w40; tapS[tid][1] = w20; tapS[tid][2] = w10;
        tapS[tid][3] = w11 + w21 + w41;
        tapS[tid][4] = w12; tapS[tid][5] = w22; tapS[tid][6] = w42;
        biasS[tid] = cb0[c] + cb1[c] + cb2[c];
        preS[tid]  = pre_w[c];
        float lwc = lw[c];
        lwS[tid] = lwc;
        pwlwS[tid] = post_w[c] * lwc;
    }
    if (tid < 136) {
        int lg = l0 - 4 + tid;
        ivs[tid] = (lg >= 0 && lg < LL) ? invr[b * LL + lg] : 0.f;
    }
    __syncthreads();

    const int li = tid & 31, ci = tid >> 5;
    const int lq = l0 + li * 4;
    float iv[12];
    #pragma unroll
    for (int j = 0; j < 12; ++j) iv[j] = ivs[li * 4 + j];

    const int ia = (lq - 4 < 0) ? 0 : lq - 4;
    const int ic = (lq + 4 > LL - 4) ? LL - 4 : lq + 4;

    float ass[4] = {}, adp[4] = {}, adx[4] = {};
    const float* xbase = x + ((size_t)(b * CC + c0)) * LL;
    const unsigned short* gbase = gate + ((size_t)(b * CC + c0)) * LL;

    #pragma unroll
    for (int j = 0; j < 8; ++j) {
        const int cl = ci * 8 + j;
        const float* xr = xbase + (size_t)cl * LL;
        f32x4 xa = *(const f32x4*)(xr + ia);
        f32x4 xm = *(const f32x4*)(xr + lq);
        f32x4 xc = *(const f32x4*)(xr + ic);
        uint2 gu = *(const uint2*)(gbase + (size_t)cl * LL + lq);
        float g[4];
        g[0] = bf2f((unsigned short)(gu.x & 0xffff));
        g[1] = bf2f((unsigned short)(gu.x >> 16));
        g[2] = bf2f((unsigned short)(gu.y & 0xffff));
        g[3] = bf2f((unsigned short)(gu.y >> 16));
        float z[12];
        #pragma unroll
        for (int r = 0; r < 4; ++r) {
            z[r]     = xa[r] * iv[r];
            z[r + 4] = xm[r] * iv[r + 4];
            z[r + 8] = xc[r] * iv[r + 8];
        }
        const float t0 = tapS[cl][0], t1 = tapS[cl][1], t2 = tapS[cl][2],
                    t3 = tapS[cl][3], t4 = tapS[cl][4], t5 = tapS[cl][5],
                    t6 = tapS[cl][6];
        const float pre = preS[cl], bias = biasS[cl], pwlw = pwlwS[cl], lwc = lwS[cl];
        #pragma unroll
        for (int k = 0; k < 4; ++k) {
            float s = t0 * z[k] + t1 * z[k + 2] + t2 * z[k + 3] + t3 * z[k + 4]
                    + t4 * z[k + 5] + t5 * z[k + 6] + t6 * z[k + 8];
            float p = (pre * s + bias) * g[k];
            ass[k] += p * p;
            adp[k] += p * pwlw;
            adx[k] += xm[k] * lwc;
        }
    }
    #pragma unroll
    for (int k = 0; k < 4; ++k) {
        red[ci][li * 4 + k][0] = ass[k];
        red[ci][li * 4 + k][1] = adp[k];
        red[ci][li * 4 + k][2] = adx[k];
    }
    __syncthreads();
    if (tid < 128) {
        float s0 = 0.f, s1 = 0.f, s2 = 0.f;
        #pragma unroll
        for (int g2 = 0; g2 < 8; ++g2) {
            s0 += red[g2][tid][0];
            s1 += red[g2][tid][1];
            s2 += red[g2][tid][2];
        }
        float* pp = part + (((size_t)(b * 8 + cc)) * LL + l0 + tid) * 3;
        pp[0] = s0; pp[1] = s1; pp[2] = s2;
    }
}

// ------- K3b: combine 8 chunk-partials -> out -------
__global__ __launch_bounds__(256) void k3b(
    const float* __restrict__ part, float* __restrict__ out) {
    int gl = blockIdx.x * 256 + threadIdx.x;   // B*L = 32768
    int b = gl >> 11, l = gl & 2047;
    float s0 = 0.f, s1 = 0.f, s2 = 0.f;
    #pragma unroll
    for (int cc2 = 0; cc2 < 8; ++cc2) {
        const float* pp = part + (((size_t)(b * 8 + cc2)) * LL + l) * 3;
        s0 += pp[0]; s1 += pp[1]; s2 += pp[2];
    }
    out[gl] = s2 + rsqrtf(s0 * (1.0f / CC) + 1e-5f) * s1;
}

extern "C" void kernel_launch(void* const* d_in, const int* in_sizes, int n_in,
                              void* d_out, int out_size, void* d_ws, size_t ws_size,
                              hipStream_t stream) {
    const float* x      = (const float*)d_in[1];
    const float* pre_w  = (const float*)d_in[2];
    const float* cw0    = (const float*)d_in[3];
    const float* cb0    = (const float*)d_in[4];
    const float* cw1    = (const float*)d_in[5];
    const float* cb1    = (const float*)d_in[6];
    const float* cw2    = (const float*)d_in[7];
    const float* cb2    = (const float*)d_in[8];
    const float* gw     = (const float*)d_in[9];
    const float* gb     = (const float*)d_in[10];
    const float* post_w = (const float*)d_in[11];
    const float* lw     = (const float*)d_in[12];
    float* out = (float*)d_out;

    // ws layout (bytes): gw_bf16 0..524288 | x_norm_T 524288..34078720 |
    // inv_rms ..34209792 | gate ..67764224
    // part (3.1MB) aliases x_norm_T (dead after k2).
    char* ws = (char*)d_ws;
    unsigned short* gwb  = (unsigned short*)(ws);
    unsigned short* xnt  = (unsigned short*)(ws + 524288);
    float*          invr = (float*)(ws + 524288 + 33554432);
    unsigned short* gate = (unsigned short*)(ws + 524288 + 33554432 + 131072);
    float*          part = (float*)(ws + 524288);   // alias, dead xnt

    hipLaunchKernelGGL(k0_cast,  dim3((CC * CC + 255) / 256), dim3(256), 0, stream, gw, gwb);
    hipLaunchKernelGGL(k1_rms_t, dim3(BB * (LL / 32)),        dim3(256), 0, stream, x, pre_w, xnt, invr);
    hipLaunchKernelGGL(k2_gemm,  dim3(LL / 256, CC / 256, BB), dim3(512), 0, stream, gwb, xnt, gb, gate);
    hipLaunchKernelGGL(k3a,      dim3(LL / 128, CC / 64, BB), dim3(256), 0, stream,
                       x, invr, gate, cw0, cb0, cw1, cb1, cw2, cb2, pre_w, post_w, lw, part);
    hipLaunchKernelGGL(k3b,      dim3(BB * LL / 256),         dim3(256), 0, stream, part, out);
}